// Round 1
// baseline (133.959 us; speedup 1.0000x reference)
//
#include <hip/hip_runtime.h>
#include <math.h>

#define BATCH   256
#define NQ      1000
#define NC      80
#define NDET    300
#define THREADS 1024
#define SCORE_TH 0.05f

typedef unsigned long long u64;

// key = (sigmoid_bits << 32) | ((1023 - q) << 10) | label
//   u64-descending == (score desc, q asc) == jax.lax.top_k's stable order.

// ---------------------------------------------------------------------------
// Kernel 1: streaming per-query argmax -> sigmoid -> packed key to workspace.
// grid (16, BATCH) x 256 threads. Block (cx, b) covers queries cx*64..cx*64+63.
// 4-lane group per query: lane r loads 5 float4 (64B chunks), 20-way compare,
// 2-round shfl_xor merge. No LDS, no barriers -> deep occupancy, pure stream.
// ---------------------------------------------------------------------------
__global__ __launch_bounds__(256) void rtdetr_reduce(
    const float* __restrict__ logits,   // [B, Q, C]
    u64* __restrict__ keys)             // [B, 1024] (entries >= NQ unwritten)
{
    const int b  = blockIdx.y;
    const int t  = threadIdx.x;
    const int r  = t & 3;               // sub-slice within 4-lane group
    const int g  = t >> 2;              // group id 0..63
    const int q  = blockIdx.x * 64 + g; // only last chunk can exceed NQ-1
    const int qc = min(q, NQ - 1);      // clamp address, guard the store

    const float4* A = (const float4*)(logits + (size_t)b * NQ * NC)
                      + (size_t)qc * 20;

    float4 va[5];
    #pragma unroll
    for (int i = 0; i < 5; ++i) va[i] = A[4 * i + r];

    float bv = -1e30f; int bc = 0;
    #pragma unroll
    for (int i = 0; i < 5; ++i) {
        float4 v = va[i]; int c = 16 * i + 4 * r;
        if (v.x > bv) { bv = v.x; bc = c + 0; }   // strict >: lowest class wins
        if (v.y > bv) { bv = v.y; bc = c + 1; }
        if (v.z > bv) { bv = v.z; bc = c + 2; }
        if (v.w > bv) { bv = v.w; bc = c + 3; }
    }
    #pragma unroll
    for (int d = 1; d <= 2; d <<= 1) {
        float ov = __shfl_xor(bv, d);
        int   oc = __shfl_xor(bc, d);
        if (ov > bv || (ov == bv && oc < bc)) { bv = ov; bc = oc; }
    }
    if (r == 0 && q < NQ) {
        float sc = 1.0f / (1.0f + expf(-bv));
        unsigned int key = (sc > SCORE_TH) ? __float_as_uint(sc) : 0u;
        keys[((size_t)b << 10) + q] = ((u64)key << 32) |
            ((unsigned int)(1023 - q) << 10) | (unsigned int)bc;
    }
}

// ---------------------------------------------------------------------------
// Kernel 2: per-batch hybrid bitonic sort of the 1024 keys + emit.
// grid BATCH x 1024 threads. j<64 via shfl (no barrier); j>=64 via LDS.
// ---------------------------------------------------------------------------
__global__ __launch_bounds__(THREADS) void rtdetr_sort(
    const u64* __restrict__ keys,       // [B, 1024]
    const float* __restrict__ boxes,    // [B, Q, 4]
    const float* __restrict__ sizes,    // [B, 2] (h, w)
    float* __restrict__ out)
{
    __shared__ u64    s_k[THREADS];     // 8 KB
    __shared__ float4 s_box[NQ];        // 16 KB

    const int b = blockIdx.x;
    const int t = threadIdx.x;

    if (t < NQ) s_box[t] = ((const float4*)boxes)[b * NQ + t];
    u64 v = (t < NQ) ? keys[((size_t)b << 10) + t] : 0ull;  // pad sorts last

    // bitonic sort, descending; first LDS phase's barrier also orders s_box
    for (int k = 2; k <= THREADS; k <<= 1) {
        for (int j = k >> 1; j > 0; j >>= 1) {
            u64 o;
            if (j >= 64) {
                __syncthreads();          // protect previous reads of s_k
                s_k[t] = v;
                __syncthreads();
                o = s_k[t ^ j];
            } else {
                o = __shfl_xor(v, j);
            }
            const bool takeMax = (((t & j) == 0) == ((t & k) == 0));
            if (takeMax ? (o > v) : (o < v)) v = o;
        }
    }

    // emit: thread t holds the exact stable rank-t entry
    if (t < NDET) {
        unsigned int key = (unsigned int)(v >> 32);

        float* out_scores = out;
        float* out_labels = out + (size_t)BATCH * NDET;
        float* out_boxes  = out + (size_t)2 * BATCH * NDET;
        const int o = b * NDET + t;

        if (key != 0u) {
            int lab = (int)(v & 0x3FFull);
            int idx = 1023 - (int)((v >> 10) & 0x3FFull);
            out_scores[o] = __uint_as_float(key);
            out_labels[o] = (float)lab;
            float4 bx = s_box[idx];                  // cx, cy, w, h (LDS gather)
            const float img_h = sizes[2 * b + 0];
            const float img_w = sizes[2 * b + 1];
            float4 ob;
            ob.x = (bx.x - 0.5f * bx.z) * img_w;
            ob.y = (bx.y - 0.5f * bx.w) * img_h;
            ob.z = (bx.x + 0.5f * bx.z) * img_w;
            ob.w = (bx.y + 0.5f * bx.w) * img_h;
            ((float4*)out_boxes)[o] = ob;
        } else {
            out_scores[o] = 0.0f;
            out_labels[o] = -1.0f;
            ((float4*)out_boxes)[o] = make_float4(0.0f, 0.0f, 0.0f, 0.0f);
        }
    }
}

// ---------------------------------------------------------------------------
// Fallback: previous fused single-kernel version (used if workspace too small).
// ---------------------------------------------------------------------------
__global__ __launch_bounds__(THREADS) void rtdetr_fused(
    const float* __restrict__ logits,
    const float* __restrict__ boxes,
    const float* __restrict__ sizes,
    float* __restrict__ out)
{
    __shared__ u64    s_k[THREADS];
    __shared__ float4 s_box[NQ];

    const int b = blockIdx.x;
    const int t = threadIdx.x;

    if (t < NQ) s_box[t] = ((const float4*)boxes)[b * NQ + t];
    if (t >= NQ) s_k[t] = 0ull;

    const int r = t & 3;
    const int g = t >> 2;
    const float4* gbase = (const float4*)(logits + (size_t)b * NQ * NC);

    #pragma unroll
    for (int pp = 0; pp < 2; ++pp) {
        const int qa = (2 * pp + 0) * 256 + g;
        const int qb = (2 * pp + 1) * 256 + g;
        const int qbc = min(qb, NQ - 1);

        const float4* A = gbase + (size_t)qa * 20;
        const float4* B = gbase + (size_t)qbc * 20;

        float4 va[5], vb[5];
        #pragma unroll
        for (int i = 0; i < 5; ++i) va[i] = A[4 * i + r];
        #pragma unroll
        for (int i = 0; i < 5; ++i) vb[i] = B[4 * i + r];

        {
            float bv = -1e30f; int bc = 0;
            #pragma unroll
            for (int i = 0; i < 5; ++i) {
                float4 v = va[i]; int c = 16 * i + 4 * r;
                if (v.x > bv) { bv = v.x; bc = c + 0; }
                if (v.y > bv) { bv = v.y; bc = c + 1; }
                if (v.z > bv) { bv = v.z; bc = c + 2; }
                if (v.w > bv) { bv = v.w; bc = c + 3; }
            }
            #pragma unroll
            for (int d = 1; d <= 2; d <<= 1) {
                float ov = __shfl_xor(bv, d);
                int   oc = __shfl_xor(bc, d);
                if (ov > bv || (ov == bv && oc < bc)) { bv = ov; bc = oc; }
            }
            if (r == 0) {
                float sc = 1.0f / (1.0f + expf(-bv));
                unsigned int key = (sc > SCORE_TH) ? __float_as_uint(sc) : 0u;
                s_k[qa] = ((u64)key << 32) |
                          ((unsigned int)(1023 - qa) << 10) | (unsigned int)bc;
            }
        }
        {
            float bv = -1e30f; int bc = 0;
            #pragma unroll
            for (int i = 0; i < 5; ++i) {
                float4 v = vb[i]; int c = 16 * i + 4 * r;
                if (v.x > bv) { bv = v.x; bc = c + 0; }
                if (v.y > bv) { bv = v.y; bc = c + 1; }
                if (v.z > bv) { bv = v.z; bc = c + 2; }
                if (v.w > bv) { bv = v.w; bc = c + 3; }
            }
            #pragma unroll
            for (int d = 1; d <= 2; d <<= 1) {
                float ov = __shfl_xor(bv, d);
                int   oc = __shfl_xor(bc, d);
                if (ov > bv || (ov == bv && oc < bc)) { bv = ov; bc = oc; }
            }
            if (r == 0 && qb < NQ) {
                float sc = 1.0f / (1.0f + expf(-bv));
                unsigned int key = (sc > SCORE_TH) ? __float_as_uint(sc) : 0u;
                s_k[qb] = ((u64)key << 32) |
                          ((unsigned int)(1023 - qb) << 10) | (unsigned int)bc;
            }
        }
    }
    __syncthreads();

    u64 v = s_k[t];
    for (int k = 2; k <= THREADS; k <<= 1) {
        for (int j = k >> 1; j > 0; j >>= 1) {
            u64 o;
            if (j >= 64) {
                __syncthreads();
                s_k[t] = v;
                __syncthreads();
                o = s_k[t ^ j];
            } else {
                o = __shfl_xor(v, j);
            }
            const bool takeMax = (((t & j) == 0) == ((t & k) == 0));
            if (takeMax ? (o > v) : (o < v)) v = o;
        }
    }

    if (t < NDET) {
        unsigned int key = (unsigned int)(v >> 32);

        float* out_scores = out;
        float* out_labels = out + (size_t)BATCH * NDET;
        float* out_boxes  = out + (size_t)2 * BATCH * NDET;
        const int o = b * NDET + t;

        if (key != 0u) {
            int lab = (int)(v & 0x3FFull);
            int idx = 1023 - (int)((v >> 10) & 0x3FFull);
            out_scores[o] = __uint_as_float(key);
            out_labels[o] = (float)lab;
            float4 bx = s_box[idx];
            const float img_h = sizes[2 * b + 0];
            const float img_w = sizes[2 * b + 1];
            float4 ob;
            ob.x = (bx.x - 0.5f * bx.z) * img_w;
            ob.y = (bx.y - 0.5f * bx.w) * img_h;
            ob.z = (bx.x + 0.5f * bx.z) * img_w;
            ob.w = (bx.y + 0.5f * bx.w) * img_h;
            ((float4*)out_boxes)[o] = ob;
        } else {
            out_scores[o] = 0.0f;
            out_labels[o] = -1.0f;
            ((float4*)out_boxes)[o] = make_float4(0.0f, 0.0f, 0.0f, 0.0f);
        }
    }
}

extern "C" void kernel_launch(void* const* d_in, const int* in_sizes, int n_in,
                              void* d_out, int out_size, void* d_ws, size_t ws_size,
                              hipStream_t stream) {
    const float* logits = (const float*)d_in[0];   // [256,1000,80]
    const float* boxes  = (const float*)d_in[1];   // [256,1000,4]
    const float* sizes  = (const float*)d_in[2];   // [256,2]
    float* out = (float*)d_out;                    // 460800 floats

    const size_t need = (size_t)BATCH * 1024 * sizeof(u64); // 2 MiB of keys
    if (d_ws != nullptr && ws_size >= need) {
        u64* keys = (u64*)d_ws;
        dim3 g1(16, BATCH);
        rtdetr_reduce<<<g1, 256, 0, stream>>>(logits, keys);
        rtdetr_sort<<<BATCH, THREADS, 0, stream>>>(keys, boxes, sizes, out);
    } else {
        rtdetr_fused<<<BATCH, THREADS, 0, stream>>>(logits, boxes, sizes, out);
    }
}

// Round 2
// 131.989 us; speedup vs baseline: 1.0149x; 1.0149x over previous
//
#include <hip/hip_runtime.h>
#include <math.h>

#define BATCH   256
#define NQ      1000
#define NC      80
#define NDET    300
#define THREADS 1024
#define SCORE_TH 0.05f

typedef unsigned long long u64;

// Fused: per-query argmax -> packed key in LDS -> hybrid bitonic sort -> emit.
// key = (sigmoid_bits << 32) | ((1023 - q) << 10) | label
//   sigmoid_bits = fp32 bits of sigmoid(max logit) if > 0.05 else 0
//   u64-descending == (score desc, q asc) == jax.lax.top_k's stable order;
//   label bits never affect order (the (1023-q) field is unique per q).

// argmax over one query's 80 logits, spread across a 4-lane group.
// After the 2-round butterfly ALL 4 lanes hold the group winner.
__device__ __forceinline__ void argmax20(const float4* v, int r,
                                         float& bv_out, int& bc_out)
{
    float bv = -1e30f; int bc = 0;
    #pragma unroll
    for (int i = 0; i < 5; ++i) {
        float4 x = v[i]; int c = 16 * i + 4 * r;
        if (x.x > bv) { bv = x.x; bc = c + 0; }   // strict >: lowest class wins
        if (x.y > bv) { bv = x.y; bc = c + 1; }
        if (x.z > bv) { bv = x.z; bc = c + 2; }
        if (x.w > bv) { bv = x.w; bc = c + 3; }
    }
    #pragma unroll
    for (int d = 1; d <= 2; d <<= 1) {
        float ov = __shfl_xor(bv, d);
        int   oc = __shfl_xor(bc, d);
        if (ov > bv || (ov == bv && oc < bc)) { bv = ov; bc = oc; }
    }
    bv_out = bv; bc_out = bc;
}

__global__ __launch_bounds__(THREADS) void rtdetr_fused(
    const float* __restrict__ logits,   // [B, Q, C]
    const float* __restrict__ boxes,    // [B, Q, 4]
    const float* __restrict__ sizes,    // [B, 2] (h, w)
    float* __restrict__ out)            // scores | labels | boxes
{
    __shared__ u64    s_k[THREADS];     // 8 KB
    __shared__ float4 s_box[NQ];        // 16 KB

    const int b = blockIdx.x;
    const int t = threadIdx.x;
    const int r = t & 3;                // sub-slice within 4-lane group
    const int g = t >> 2;               // group id 0..255

    // Stage boxes row into a REGISTER now (load issues, no consumer -> no
    // vmcnt stall); the LDS write is deferred until after phase A so the
    // logit load stream starts immediately.
    float4 boxreg = make_float4(0.0f, 0.0f, 0.0f, 0.0f);
    if (t < NQ) boxreg = ((const float4*)boxes)[b * NQ + t];

    const float4* gbase = (const float4*)(logits + (size_t)b * NQ * NC);

    // ---- phase A: 2 superpasses x 2 queries; ALL loads unconditional ----
    // queries for this group: p*256 + g, p=0..3; only p=3 can exceed NQ-1.
    float q0v, q1v, q2v, q3v; int q0c, q1c, q2c, q3c;
    {
        const float4* A = gbase + (size_t)(g      ) * 20;
        const float4* B = gbase + (size_t)(256 + g) * 20;
        float4 va[5], vb[5];
        #pragma unroll
        for (int i = 0; i < 5; ++i) va[i] = A[4 * i + r];
        #pragma unroll
        for (int i = 0; i < 5; ++i) vb[i] = B[4 * i + r];
        argmax20(va, r, q0v, q0c);
        argmax20(vb, r, q1v, q1c);
    }
    {
        const int qlast = min(768 + g, NQ - 1);       // clamp address
        const float4* A = gbase + (size_t)(512 + g) * 20;
        const float4* B = gbase + (size_t)qlast * 20;
        float4 va[5], vb[5];
        #pragma unroll
        for (int i = 0; i < 5; ++i) va[i] = A[4 * i + r];
        #pragma unroll
        for (int i = 0; i < 5; ++i) vb[i] = B[4 * i + r];
        argmax20(va, r, q2v, q2c);
        argmax20(vb, r, q3v, q3c);
    }

    // Lane-spread key emission: every lane holds all 4 winners (butterfly
    // broadcast); lane r takes query r*256+g -> one sigmoid + one ds_write
    // per thread instead of 4 serial ones on r==0 lanes.
    // Explicit selection (no runtime-indexed array -> stays in registers).
    float mv = (r == 0) ? q0v : (r == 1) ? q1v : (r == 2) ? q2v : q3v;
    int   mc = (r == 0) ? q0c : (r == 1) ? q1c : (r == 2) ? q2c : q3c;
    const int mq = (r << 8) + g;                      // bijective over 0..1023

    float sc = 1.0f / (1.0f + expf(-mv));
    unsigned int kb = (sc > SCORE_TH) ? __float_as_uint(sc) : 0u;
    u64 kk = ((u64)kb << 32) |
             ((unsigned int)(1023 - mq) << 10) | (unsigned int)mc;
    if (mq >= NQ) kk = 0ull;                          // pad entries sort last
    s_k[mq] = kk;
    if (t < NQ) s_box[t] = boxreg;                    // deferred LDS stage
    __syncthreads();

    // ---- phase B: hybrid bitonic sort, descending ----
    // j<64 via shfl (no barrier); j>=64 via LDS (10 phases x 2 barriers)
    u64 v = s_k[t];
    for (int k = 2; k <= THREADS; k <<= 1) {
        for (int j = k >> 1; j > 0; j >>= 1) {
            u64 o;
            if (j >= 64) {
                __syncthreads();          // protect previous reads of s_k
                s_k[t] = v;
                __syncthreads();
                o = s_k[t ^ j];
            } else {
                o = __shfl_xor(v, j);
            }
            const bool takeMax = (((t & j) == 0) == ((t & k) == 0));
            if (takeMax ? (o > v) : (o < v)) v = o;
        }
    }

    // ---- emit: thread t holds the exact stable rank-t entry ----
    if (t < NDET) {
        unsigned int key = (unsigned int)(v >> 32);

        float* out_scores = out;
        float* out_labels = out + (size_t)BATCH * NDET;
        float* out_boxes  = out + (size_t)2 * BATCH * NDET;
        const int o = b * NDET + t;

        if (key != 0u) {
            int lab = (int)(v & 0x3FFull);
            int idx = 1023 - (int)((v >> 10) & 0x3FFull);
            out_scores[o] = __uint_as_float(key);
            out_labels[o] = (float)lab;
            float4 bx = s_box[idx];                  // cx, cy, w, h (LDS gather)
            const float img_h = sizes[2 * b + 0];
            const float img_w = sizes[2 * b + 1];
            float4 ob;
            ob.x = (bx.x - 0.5f * bx.z) * img_w;
            ob.y = (bx.y - 0.5f * bx.w) * img_h;
            ob.z = (bx.x + 0.5f * bx.z) * img_w;
            ob.w = (bx.y + 0.5f * bx.w) * img_h;
            ((float4*)out_boxes)[o] = ob;
        } else {
            out_scores[o] = 0.0f;
            out_labels[o] = -1.0f;
            ((float4*)out_boxes)[o] = make_float4(0.0f, 0.0f, 0.0f, 0.0f);
        }
    }
}

extern "C" void kernel_launch(void* const* d_in, const int* in_sizes, int n_in,
                              void* d_out, int out_size, void* d_ws, size_t ws_size,
                              hipStream_t stream) {
    const float* logits = (const float*)d_in[0];   // [256,1000,80]
    const float* boxes  = (const float*)d_in[1];   // [256,1000,4]
    const float* sizes  = (const float*)d_in[2];   // [256,2]
    float* out = (float*)d_out;                    // 460800 floats

    rtdetr_fused<<<BATCH, THREADS, 0, stream>>>(logits, boxes, sizes, out);
}